// Round 2
// baseline (2098.086 us; speedup 1.0000x reference)
//
#include <hip/hip_runtime.h>
#include <hip/hip_bf16.h>
#include <math.h>

// ConformerBlock on MI355X. B=4, S=4096, D=512, H=8, Hd=64, CTX=128, FFN=2048, KS=31.
// fp32 inputs/outputs (per reference). GEMMs run bf16 MFMA with weights converted
// fp32->bf16 into ws each call; residual stream kept fp32 in ws.

using bf16 = __hip_bfloat16;
typedef __bf16 bf16x8_t __attribute__((ext_vector_type(8)));
typedef float f32x4_t __attribute__((ext_vector_type(4)));

static __device__ __forceinline__ float bf2f(bf16 v) { return __bfloat162float(v); }
static __device__ __forceinline__ bf16 f2bf(float v) { return __float2bfloat16(v); }

// ---------------- fp32 -> bf16 conversion (weights), 8 elems/thread ----------------
__global__ __launch_bounds__(256) void k_f2b(const float* __restrict__ in, bf16* __restrict__ out) {
    int i = blockIdx.x * 256 + threadIdx.x;
    float4 a = *(const float4*)(in + (size_t)i * 8);
    float4 b = *(const float4*)(in + (size_t)i * 8 + 4);
    union { uint4 u; bf16 h[8]; } t;
    t.h[0] = f2bf(a.x); t.h[1] = f2bf(a.y); t.h[2] = f2bf(a.z); t.h[3] = f2bf(a.w);
    t.h[4] = f2bf(b.x); t.h[5] = f2bf(b.y); t.h[6] = f2bf(b.z); t.h[7] = f2bf(b.w);
    *(uint4*)(out + (size_t)i * 8) = t.u;
}

// ---------------- LayerNorm: fp32 in -> bf16 (or fp32) out, one wave per row of 512 ----------------
template <bool BF16OUT>
__global__ __launch_bounds__(64) void k_ln(const float* __restrict__ x, const float* __restrict__ g,
                                           const float* __restrict__ b, void* __restrict__ outp) {
    int row = blockIdx.x, t = threadIdx.x;
    const float* xr = x + (size_t)row * 512 + t * 8;
    float4 v0 = *(const float4*)xr;
    float4 v1 = *(const float4*)(xr + 4);
    float vals[8] = {v0.x, v0.y, v0.z, v0.w, v1.x, v1.y, v1.z, v1.w};
    float s = 0.f, ss = 0.f;
#pragma unroll
    for (int j = 0; j < 8; ++j) { s += vals[j]; ss += vals[j] * vals[j]; }
#pragma unroll
    for (int o = 32; o > 0; o >>= 1) { s += __shfl_xor(s, o, 64); ss += __shfl_xor(ss, o, 64); }
    float mean = s * (1.0f / 512.0f);
    float var  = ss * (1.0f / 512.0f) - mean * mean;
    float r = rsqrtf(var + 1e-5f);
    float4 g0 = *(const float4*)(g + t * 8);
    float4 g1 = *(const float4*)(g + t * 8 + 4);
    float4 b0 = *(const float4*)(b + t * 8);
    float4 b1 = *(const float4*)(b + t * 8 + 4);
    float gv[8] = {g0.x, g0.y, g0.z, g0.w, g1.x, g1.y, g1.z, g1.w};
    float bv[8] = {b0.x, b0.y, b0.z, b0.w, b1.x, b1.y, b1.z, b1.w};
    float ov[8];
#pragma unroll
    for (int j = 0; j < 8; ++j) ov[j] = (vals[j] - mean) * r * gv[j] + bv[j];
    if (BF16OUT) {
        union { uint4 u; bf16 h[8]; } oo;
#pragma unroll
        for (int j = 0; j < 8; ++j) oo.h[j] = f2bf(ov[j]);
        *(uint4*)((bf16*)outp + (size_t)row * 512 + t * 8) = oo.u;
    } else {
        float* op = (float*)outp + (size_t)row * 512 + t * 8;
        *(float4*)op = make_float4(ov[0], ov[1], ov[2], ov[3]);
        *(float4*)(op + 4) = make_float4(ov[4], ov[5], ov[6], ov[7]);
    }
}

// ---------------- bf16 MFMA GEMM: C = A[M,K] @ B[K,N] + bias, 64x64 tile ----------------
// MODE 0: store bf16.  MODE 1: exact GELU then store bf16.  MODE 2: fp32 out += scale*(acc+bias).
template <int MODE>
__global__ __launch_bounds__(256) void k_gemm(const bf16* __restrict__ A, const bf16* __restrict__ B,
                                              const float* __restrict__ bias, void* __restrict__ outp,
                                              int M, int N, int K, float scale) {
    __shared__ __align__(16) bf16 As[64][40];   // [m][k], +8 pad
    __shared__ __align__(16) bf16 Bs[64][40];   // [n][k] (transposed), +8 pad
    int bn = blockIdx.x * 64, bm = blockIdx.y * 64;
    int tid = threadIdx.x;
    int wid = tid >> 6, lane = tid & 63;
    int wm = (wid >> 1) * 32, wn = (wid & 1) * 32;
    int l15 = lane & 15, quad = lane >> 4;
    f32x4_t acc[2][2] = {};
    int arow = tid >> 2, acolb = (tid & 3) * 8;   // A tile 64x32: 16B per thread
    int brow = tid >> 3, bcolb = (tid & 7) * 8;   // B tile 32x64: 16B per thread

    for (int k0 = 0; k0 < K; k0 += 32) {
        __syncthreads();
        uint4 av = *(const uint4*)(A + (size_t)(bm + arow) * K + k0 + acolb);
        *(uint4*)&As[arow][acolb] = av;
        union { uint4 u; bf16 h[8]; } tb;
        tb.u = *(const uint4*)(B + (size_t)(k0 + brow) * N + bn + bcolb);
#pragma unroll
        for (int j = 0; j < 8; ++j) Bs[bcolb + j][brow] = tb.h[j];
        __syncthreads();
#pragma unroll
        for (int tm = 0; tm < 2; ++tm) {
            bf16x8_t af = *(const bf16x8_t*)&As[wm + tm * 16 + l15][quad * 8];
#pragma unroll
            for (int tn = 0; tn < 2; ++tn) {
                bf16x8_t bfr = *(const bf16x8_t*)&Bs[wn + tn * 16 + l15][quad * 8];
                acc[tm][tn] = __builtin_amdgcn_mfma_f32_16x16x32_bf16(af, bfr, acc[tm][tn], 0, 0, 0);
            }
        }
    }
#pragma unroll
    for (int tm = 0; tm < 2; ++tm)
#pragma unroll
        for (int tn = 0; tn < 2; ++tn) {
            int gcol = bn + wn + tn * 16 + l15;
            float bv = bias[gcol];
#pragma unroll
            for (int r = 0; r < 4; ++r) {
                int grow = bm + wm + tm * 16 + quad * 4 + r;
                float v = acc[tm][tn][r] + bv;
                if (MODE == 0) {
                    ((bf16*)outp)[(size_t)grow * N + gcol] = f2bf(v);
                } else if (MODE == 1) {
                    float gl = 0.5f * v * (1.0f + erff(v * 0.70710678118654752f));
                    ((bf16*)outp)[(size_t)grow * N + gcol] = f2bf(gl);
                } else {
                    ((float*)outp)[(size_t)grow * N + gcol] += scale * v;
                }
            }
        }
}

// ---------------- windowed local attention ----------------
// grid: B*H*nb = 1024 blocks, 128 threads (1 per query). Online softmax over 384 keys.
__global__ __launch_bounds__(128) void k_attn(const bf16* __restrict__ q, const bf16* __restrict__ k,
                                              const bf16* __restrict__ v, const float* __restrict__ rel_bias,
                                              bf16* __restrict__ out) {
    __shared__ __align__(16) bf16 kc[64][64];
    __shared__ __align__(16) bf16 vc[64][64];
    __shared__ float relb[257];
    int blk = blockIdx.x;
    int n = blk & 31, h = (blk >> 5) & 7, b = blk >> 8;
    int qi = threadIdx.x;
    for (int i = qi; i < 257; i += 128) relb[i] = rel_bias[h * 257 + i];
    int srow = n * 128 + qi;
    const bf16* qp = q + (size_t)(b * 4096 + srow) * 512 + h * 64;
    float qreg[64];
#pragma unroll
    for (int i = 0; i < 8; ++i) {
        union { uint4 u; bf16 hh[8]; } t;
        t.u = *(const uint4*)(qp + i * 8);
#pragma unroll
        for (int j = 0; j < 8; ++j) qreg[i * 8 + j] = bf2f(t.hh[j]);
    }
    float o[64];
#pragma unroll
    for (int i = 0; i < 64; ++i) o[i] = 0.f;
    float m_run = -1e30f, l_run = 0.f;
    int r = threadIdx.x >> 1, hf = threadIdx.x & 1;
    for (int ch = 0; ch < 6; ++ch) {
        int jbase = ch * 64;
        int skey = n * 128 - 128 + jbase + r;
        __syncthreads();
        {
            uint4* dk = (uint4*)&kc[r][hf * 32];
            uint4* dv = (uint4*)&vc[r][hf * 32];
            if (skey >= 0 && skey < 4096) {
                const uint4* sk = (const uint4*)(k + (size_t)(b * 4096 + skey) * 512 + h * 64 + hf * 32);
                const uint4* sv = (const uint4*)(v + (size_t)(b * 4096 + skey) * 512 + h * 64 + hf * 32);
#pragma unroll
                for (int i = 0; i < 4; ++i) { dk[i] = sk[i]; dv[i] = sv[i]; }
            } else {
                uint4 z = {0, 0, 0, 0};
#pragma unroll
                for (int i = 0; i < 4; ++i) { dk[i] = z; dv[i] = z; }
            }
        }
        __syncthreads();
        for (int jj = 0; jj < 64; ++jj) {
            int jw = jbase + jj;
            int rel = jw - 128 - qi;
            int sk2 = n * 128 - 128 + jw;
            if (rel < -128 || rel > 128 || sk2 < 0 || sk2 >= 4096) continue;
            const __hip_bfloat162* kr = (const __hip_bfloat162*)&kc[jj][0];
            float s = 0.f;
#pragma unroll
            for (int d2 = 0; d2 < 32; ++d2) {
                float2 f = __bfloat1622float2(kr[d2]);
                s += qreg[2 * d2] * f.x + qreg[2 * d2 + 1] * f.y;
            }
            s = s * 0.125f + relb[rel + 128];
            float mn = fmaxf(m_run, s);
            float p  = __expf(s - mn);
            float al = __expf(m_run - mn);
            l_run = l_run * al + p;
            const __hip_bfloat162* vr = (const __hip_bfloat162*)&vc[jj][0];
#pragma unroll
            for (int d2 = 0; d2 < 32; ++d2) {
                float2 f = __bfloat1622float2(vr[d2]);
                o[2 * d2]     = o[2 * d2] * al     + p * f.x;
                o[2 * d2 + 1] = o[2 * d2 + 1] * al + p * f.y;
            }
            m_run = mn;
        }
    }
    float inv = 1.f / l_run;
    bf16* op = out + (size_t)(b * 4096 + srow) * 512 + h * 64;
#pragma unroll
    for (int i = 0; i < 8; ++i) {
        union { uint4 u; bf16 hh[8]; } t;
#pragma unroll
        for (int j = 0; j < 8; ++j) t.hh[j] = f2bf(o[i * 8 + j] * inv);
        *(uint4*)(op + i * 8) = t.u;
    }
}

// ---------------- GLU: [16384,1024] -> [16384,512], bf16 ----------------
__global__ __launch_bounds__(256) void k_glu(const bf16* __restrict__ h, bf16* __restrict__ out) {
    int idx = blockIdx.x * 256 + threadIdx.x;
    int m = idx >> 9, c = idx & 511;
    float a = bf2f(h[(size_t)m * 1024 + c]);
    float g = bf2f(h[(size_t)m * 1024 + c + 512]);
    out[idx] = f2bf(a / (1.f + __expf(-g)));
}

// ---------------- depthwise conv (KS=31, pad 15) + BN + SiLU ----------------
__global__ __launch_bounds__(256) void k_conv(const bf16* __restrict__ in, const float* __restrict__ w,
                                              const float* __restrict__ wb, const float* __restrict__ bg,
                                              const float* __restrict__ bb2, const float* __restrict__ bm,
                                              const float* __restrict__ bvv, bf16* __restrict__ out) {
    int idx = blockIdx.x * 256 + threadIdx.x;
    int d = idx & 511, m = idx >> 9, s = m & 4095, bb = m >> 12;
    const bf16* base = in + (size_t)(bb * 4096) * 512 + d;
    float acc = 0.f;
#pragma unroll
    for (int t = 0; t < 31; ++t) {
        int ss = s + t - 15;
        if (ss >= 0 && ss < 4096)
            acc += w[d * 31 + t] * bf2f(base[(size_t)ss * 512]);
    }
    acc += wb[d];
    float sc = bg[d] * rsqrtf(bvv[d] + 1e-5f);
    acc = (acc - bm[d]) * sc + bb2[d];
    acc = acc / (1.f + __expf(-acc));
    out[idx] = f2bf(acc);
}

extern "C" void kernel_launch(void* const* d_in, const int* in_sizes, int n_in,
                              void* d_out, int out_size, void* d_ws, size_t ws_size,
                              hipStream_t stream) {
    (void)in_sizes; (void)n_in; (void)out_size; (void)ws_size;
    const float* x = (const float*)d_in[0];
    char* ws = (char*)d_ws;
    float* xf   = (float*)ws;                      // [0,32M)   fp32 residual
    bf16* ln_bf = (bf16*)(ws + 33554432);          // [32M,48M) LN output (bf16)
    bf16* h_bf  = (bf16*)(ws + 50331648);          // [48M,112M) hidden / q,k,v
    bf16* g_bf  = (bf16*)(ws + 117440512);         // [112M,128M) GLU out
    bf16* t_bf  = (bf16*)(ws + 134217728);         // [128M,144M) attn/conv out
    bf16* wc    = (bf16*)(ws + 150994944);         // [144M,...) converted weights
    bf16 *qb = h_bf, *kb = h_bf + 8388608, *vb = h_bf + 16777216;
    bf16* w_f11 = wc;                // 1048576
    bf16* w_f12 = wc + 1048576;      // 1048576
    bf16* w_f21 = wc + 2097152;      // 1048576
    bf16* w_f22 = wc + 3145728;      // 1048576
    bf16* w_q   = wc + 4194304;      // 262144
    bf16* w_k   = wc + 4456448;
    bf16* w_v   = wc + 4718592;
    bf16* w_o   = wc + 4980736;
    bf16* w_p1  = wc + 5242880;      // 524288
    bf16* w_p2  = wc + 5767168;      // 262144

    // weight fp32 -> bf16 (8 elems/thread)
    k_f2b<<<512, 256, 0, stream>>>((const float*)d_in[3],  w_f11);
    k_f2b<<<512, 256, 0, stream>>>((const float*)d_in[5],  w_f12);
    k_f2b<<<512, 256, 0, stream>>>((const float*)d_in[9],  w_f21);
    k_f2b<<<512, 256, 0, stream>>>((const float*)d_in[11], w_f22);
    k_f2b<<<128, 256, 0, stream>>>((const float*)d_in[15], w_q);
    k_f2b<<<128, 256, 0, stream>>>((const float*)d_in[16], w_k);
    k_f2b<<<128, 256, 0, stream>>>((const float*)d_in[17], w_v);
    k_f2b<<<128, 256, 0, stream>>>((const float*)d_in[18], w_o);
    k_f2b<<<256, 256, 0, stream>>>((const float*)d_in[26], w_p1);
    k_f2b<<<128, 256, 0, stream>>>((const float*)d_in[34], w_p2);

    // residual init (fp32 copy)
    hipMemcpyAsync(xf, x, 33554432, hipMemcpyDeviceToDevice, stream);

    // FFN1: x += 0.5*FFN(LN(x))
    k_ln<true><<<16384, 64, 0, stream>>>(xf, (const float*)d_in[1], (const float*)d_in[2], ln_bf);
    k_gemm<1><<<dim3(32, 256), 256, 0, stream>>>(ln_bf, w_f11, (const float*)d_in[4], h_bf, 16384, 2048, 512, 0.f);
    k_gemm<2><<<dim3(8, 256), 256, 0, stream>>>(h_bf, w_f12, (const float*)d_in[6], xf, 16384, 512, 2048, 0.5f);
    // attention
    k_ln<true><<<16384, 64, 0, stream>>>(xf, (const float*)d_in[13], (const float*)d_in[14], ln_bf);
    k_gemm<0><<<dim3(8, 256), 256, 0, stream>>>(ln_bf, w_q, (const float*)d_in[19], qb, 16384, 512, 512, 0.f);
    k_gemm<0><<<dim3(8, 256), 256, 0, stream>>>(ln_bf, w_k, (const float*)d_in[20], kb, 16384, 512, 512, 0.f);
    k_gemm<0><<<dim3(8, 256), 256, 0, stream>>>(ln_bf, w_v, (const float*)d_in[21], vb, 16384, 512, 512, 0.f);
    k_attn<<<1024, 128, 0, stream>>>(qb, kb, vb, (const float*)d_in[23], t_bf);
    k_gemm<2><<<dim3(8, 256), 256, 0, stream>>>(t_bf, w_o, (const float*)d_in[22], xf, 16384, 512, 512, 1.0f);
    // conv module
    k_ln<true><<<16384, 64, 0, stream>>>(xf, (const float*)d_in[24], (const float*)d_in[25], ln_bf);
    k_gemm<0><<<dim3(16, 256), 256, 0, stream>>>(ln_bf, w_p1, (const float*)d_in[27], h_bf, 16384, 1024, 512, 0.f);
    k_glu<<<32768, 256, 0, stream>>>(h_bf, g_bf);
    k_conv<<<32768, 256, 0, stream>>>(g_bf, (const float*)d_in[28], (const float*)d_in[29], (const float*)d_in[30],
                                      (const float*)d_in[31], (const float*)d_in[32], (const float*)d_in[33], t_bf);
    k_gemm<2><<<dim3(8, 256), 256, 0, stream>>>(t_bf, w_p2, (const float*)d_in[35], xf, 16384, 512, 512, 1.0f);
    // FFN2
    k_ln<true><<<16384, 64, 0, stream>>>(xf, (const float*)d_in[7], (const float*)d_in[8], ln_bf);
    k_gemm<1><<<dim3(32, 256), 256, 0, stream>>>(ln_bf, w_f21, (const float*)d_in[10], h_bf, 16384, 2048, 512, 0.f);
    k_gemm<2><<<dim3(8, 256), 256, 0, stream>>>(h_bf, w_f22, (const float*)d_in[12], xf, 16384, 512, 2048, 0.5f);
    // final LN -> fp32 out
    k_ln<false><<<16384, 64, 0, stream>>>(xf, (const float*)d_in[36], (const float*)d_in[37], d_out);
}

// Round 4
// 1095.452 us; speedup vs baseline: 1.9153x; 1.9153x over previous
//
#include <hip/hip_runtime.h>
#include <hip/hip_bf16.h>
#include <math.h>

// ConformerBlock on MI355X. B=4, S=4096, D=512, H=8, Hd=64, CTX=128, FFN=2048, KS=31.
// fp32 inputs/outputs. bf16 MFMA GEMMs (m97-style 128x128 tile + global_load_lds),
// MFMA flash attention. Residual stream fp32 in ws.

using bf16 = __hip_bfloat16;
typedef __bf16 bf16x8_t __attribute__((ext_vector_type(8)));
typedef float f32x4_t __attribute__((ext_vector_type(4)));

static __device__ __forceinline__ float bf2f(bf16 v) { return __bfloat162float(v); }
static __device__ __forceinline__ bf16 f2bf(float v) { return __float2bfloat16(v); }

#define GLOAD_LDS16(g, l)                                                            \
    __builtin_amdgcn_global_load_lds((const __attribute__((address_space(1))) void*)(g), \
                                     (__attribute__((address_space(3))) void*)(l), 16, 0, 0)

// ---------------- fp32 [K][N] -> bf16 transposed [N][K] ----------------
__global__ __launch_bounds__(256) void k_f2bt(const float* __restrict__ in, bf16* __restrict__ out,
                                              int K, int N) {
    __shared__ float t[32][33];
    int c = threadIdx.x & 31, r0 = threadIdx.x >> 5;
    int kb = blockIdx.y * 32, nb = blockIdx.x * 32;
#pragma unroll
    for (int i = 0; i < 4; ++i)
        t[r0 + i * 8][c] = in[(size_t)(kb + r0 + i * 8) * N + nb + c];
    __syncthreads();
#pragma unroll
    for (int i = 0; i < 4; ++i)
        out[(size_t)(nb + r0 + i * 8) * K + kb + c] = f2bf(t[c][r0 + i * 8]);
}

// ---------------- LayerNorm: fp32 in -> bf16 (or fp32) out, one wave per row ----------------
template <bool BF16OUT>
__global__ __launch_bounds__(64) void k_ln(const float* __restrict__ x, const float* __restrict__ g,
                                           const float* __restrict__ b, void* __restrict__ outp) {
    int row = blockIdx.x, t = threadIdx.x;
    const float* xr = x + (size_t)row * 512 + t * 8;
    float4 v0 = *(const float4*)xr;
    float4 v1 = *(const float4*)(xr + 4);
    float vals[8] = {v0.x, v0.y, v0.z, v0.w, v1.x, v1.y, v1.z, v1.w};
    float s = 0.f, ss = 0.f;
#pragma unroll
    for (int j = 0; j < 8; ++j) { s += vals[j]; ss += vals[j] * vals[j]; }
#pragma unroll
    for (int o = 32; o > 0; o >>= 1) { s += __shfl_xor(s, o, 64); ss += __shfl_xor(ss, o, 64); }
    float mean = s * (1.0f / 512.0f);
    float var  = ss * (1.0f / 512.0f) - mean * mean;
    float r = rsqrtf(var + 1e-5f);
    float4 g0 = *(const float4*)(g + t * 8);
    float4 g1 = *(const float4*)(g + t * 8 + 4);
    float4 b0 = *(const float4*)(b + t * 8);
    float4 b1 = *(const float4*)(b + t * 8 + 4);
    float gv[8] = {g0.x, g0.y, g0.z, g0.w, g1.x, g1.y, g1.z, g1.w};
    float bv[8] = {b0.x, b0.y, b0.z, b0.w, b1.x, b1.y, b1.z, b1.w};
    float ov[8];
#pragma unroll
    for (int j = 0; j < 8; ++j) ov[j] = (vals[j] - mean) * r * gv[j] + bv[j];
    if (BF16OUT) {
        union { uint4 u; bf16 h[8]; } oo;
#pragma unroll
        for (int j = 0; j < 8; ++j) oo.h[j] = f2bf(ov[j]);
        *(uint4*)((bf16*)outp + (size_t)row * 512 + t * 8) = oo.u;
    } else {
        float* op = (float*)outp + (size_t)row * 512 + t * 8;
        *(float4*)op = make_float4(ov[0], ov[1], ov[2], ov[3]);
        *(float4*)(op + 4) = make_float4(ov[4], ov[5], ov[6], ov[7]);
    }
}

// ---------------- m97-style GEMM: C = A[M,K] @ Bt[N,K]^T + bias, 128x128 tile ----------------
// MODE 0: bf16 store. MODE 1: exact GELU -> bf16. MODE 2: fp32 out += scale*(acc+bias).
template <int MODE>
__global__ __launch_bounds__(256) void k_gemm(const bf16* __restrict__ A, const bf16* __restrict__ Bt,
                                              const float* __restrict__ bias, void* __restrict__ outp,
                                              int M, int N, int K, float scale) {
    __shared__ __align__(16) bf16 As[128 * 32];
    __shared__ __align__(16) bf16 Bs[128 * 32];
    int bn = blockIdx.x * 128, bm = blockIdx.y * 128;
    int tid = threadIdx.x, w = tid >> 6, l = tid & 63;
    int l15 = l & 15, quad = l >> 4;
    int wm = (w >> 1) * 64, wn = (w & 1) * 64;
    f32x4_t acc[4][4] = {};
    // wave w stages rows [w*32, w*32+32): 2 insts x (64 lanes x 16B) = 16 rows each.
    // lane l's global src row = w*32 + (l>>2), cols (l&3)*8 .. +8  == LDS base + l*16B.
    const bf16* ag = A + (size_t)(bm + w * 32 + (l >> 2)) * K + (l & 3) * 8;
    const bf16* bg = Bt + (size_t)(bn + w * 32 + (l >> 2)) * K + (l & 3) * 8;
    bf16* asl = As + w * 32 * 32;   // wave-uniform LDS base
    bf16* bsl = Bs + w * 32 * 32;

    for (int k0 = 0; k0 < K; k0 += 32) {
        __syncthreads();
#pragma unroll
        for (int j = 0; j < 2; ++j) {
            GLOAD_LDS16(ag + (size_t)j * 16 * K + k0, asl + j * 16 * 32);
            GLOAD_LDS16(bg + (size_t)j * 16 * K + k0, bsl + j * 16 * 32);
        }
        __syncthreads();
        bf16x8_t af[4], bfr[4];
#pragma unroll
        for (int tm = 0; tm < 4; ++tm)
            af[tm] = *(const bf16x8_t*)(As + (wm + tm * 16 + l15) * 32 + quad * 8);
#pragma unroll
        for (int tn = 0; tn < 4; ++tn)
            bfr[tn] = *(const bf16x8_t*)(Bs + (wn + tn * 16 + l15) * 32 + quad * 8);
#pragma unroll
        for (int tm = 0; tm < 4; ++tm)
#pragma unroll
            for (int tn = 0; tn < 4; ++tn)
                acc[tm][tn] = __builtin_amdgcn_mfma_f32_16x16x32_bf16(af[tm], bfr[tn], acc[tm][tn], 0, 0, 0);
    }
#pragma unroll
    for (int tm = 0; tm < 4; ++tm)
#pragma unroll
        for (int tn = 0; tn < 4; ++tn) {
            int gcol = bn + wn + tn * 16 + l15;
            float bv = bias[gcol];
#pragma unroll
            for (int r = 0; r < 4; ++r) {
                int grow = bm + wm + tm * 16 + quad * 4 + r;
                float vv = acc[tm][tn][r] + bv;
                if (MODE == 0) {
                    ((bf16*)outp)[(size_t)grow * N + gcol] = f2bf(vv);
                } else if (MODE == 1) {
                    float gl = 0.5f * vv * (1.0f + erff(vv * 0.70710678118654752f));
                    ((bf16*)outp)[(size_t)grow * N + gcol] = f2bf(gl);
                } else {
                    ((float*)outp)[(size_t)grow * N + gcol] += scale * vv;
                }
            }
        }
}

// ---------------- MFMA flash attention over 384-key windows ----------------
// grid: B*H*nb = 1024 blocks, 256 threads (4 waves). Wave w: queries [w*32, w*32+32).
__global__ __launch_bounds__(256) void k_attn(const bf16* __restrict__ q, const bf16* __restrict__ k,
                                              const bf16* __restrict__ v, const float* __restrict__ rel_bias,
                                              bf16* __restrict__ out) {
    __shared__ __align__(16) bf16 Qs[128][72];
    __shared__ __align__(16) bf16 Ks[64][72];
    __shared__ __align__(16) bf16 Vt[64][72];
    __shared__ __align__(16) bf16 Pb[4][32][72];
    __shared__ float relb[257];
    int blk = blockIdx.x;
    int n = blk & 31, h = (blk >> 5) & 7, b = blk >> 8;
    int tid = threadIdx.x, w = tid >> 6, lane = tid & 63;
    int l15 = lane & 15, quad = lane >> 4;
    for (int i = tid; i < 257; i += 256) relb[i] = rel_bias[h * 257 + i];
    {   // stage Q block: 128 rows x 64 cols = 1024 uint4 stores
        const bf16* qg = q + (size_t)(b * 4096 + n * 128) * 512 + h * 64;
#pragma unroll
        for (int i = 0; i < 4; ++i) {
            int slot = tid + 256 * i;
            int row = slot >> 3, col = (slot & 7) * 8;
            *(uint4*)&Qs[row][col] = *(const uint4*)(qg + (size_t)row * 512 + col);
        }
    }
    float m_run[2][4], l_run[2][4];
#pragma unroll
    for (int qt = 0; qt < 2; ++qt)
#pragma unroll
        for (int r = 0; r < 4; ++r) { m_run[qt][r] = -1e30f; l_run[qt][r] = 0.f; }
    f32x4_t Oacc[2][4] = {};
    int kv0 = n * 128 - 128;
    for (int ch = 0; ch < 6; ++ch) {
        int kst = kv0 + ch * 64;
        if (kst < 0 || kst >= 4096) continue;   // uniform per block: chunk fully OOB
        __syncthreads();
        {   // stage K chunk [64 keys][64 d] = 512 uint4 stores
#pragma unroll
            for (int i = 0; i < 2; ++i) {
                int slot = tid + 256 * i;
                int row = slot >> 3, col = (slot & 7) * 8;
                *(uint4*)&Ks[row][col] = *(const uint4*)(k + (size_t)(b * 4096 + kst + row) * 512 + h * 64 + col);
            }
        }
        {   // stage V chunk transposed: Vt[d][key], 16 elems per thread
            int key = tid >> 2, c0 = (tid & 3) * 16;
            union { uint4 u[2]; bf16 hh[16]; } tv;
            const bf16* vg = v + (size_t)(b * 4096 + kst + key) * 512 + h * 64 + c0;
            tv.u[0] = *(const uint4*)vg;
            tv.u[1] = *(const uint4*)(vg + 8);
#pragma unroll
            for (int j = 0; j < 16; ++j) Vt[c0 + j][key] = tv.hh[j];
        }
        __syncthreads();
        // QK^T -> S[32 q][64 key] per wave
        bf16x8_t qf[2][2];
#pragma unroll
        for (int qt = 0; qt < 2; ++qt)
#pragma unroll
            for (int ks = 0; ks < 2; ++ks)
                qf[qt][ks] = *(const bf16x8_t*)&Qs[w * 32 + qt * 16 + l15][ks * 32 + quad * 8];
        float sc[2][4][4];
#pragma unroll
        for (int qt = 0; qt < 2; ++qt)
#pragma unroll
            for (int nt = 0; nt < 4; ++nt) {
                f32x4_t a = {};
#pragma unroll
                for (int ks = 0; ks < 2; ++ks) {
                    bf16x8_t kf = *(const bf16x8_t*)&Ks[nt * 16 + l15][ks * 32 + quad * 8];
                    a = __builtin_amdgcn_mfma_f32_16x16x32_bf16(qf[qt][ks], kf, a, 0, 0, 0);
                }
#pragma unroll
                for (int r = 0; r < 4; ++r) sc[qt][nt][r] = a[r];
            }
        // scale + rel bias + mask
#pragma unroll
        for (int qt = 0; qt < 2; ++qt)
#pragma unroll
            for (int nt = 0; nt < 4; ++nt)
#pragma unroll
                for (int r = 0; r < 4; ++r) {
                    int qrow = w * 32 + qt * 16 + quad * 4 + r;
                    int rel = ch * 64 + nt * 16 + l15 - 128 - qrow;
                    int idx = rel + 128; idx = idx < 0 ? 0 : (idx > 256 ? 256 : idx);
                    float s = sc[qt][nt][r] * 0.125f + relb[idx];
                    sc[qt][nt][r] = (rel >= -128 && rel <= 128) ? s : -INFINITY;
                }
        // online softmax per query row (rows are per-lane: quad*4+r; cols across l15)
        float al[2][4];
#pragma unroll
        for (int qt = 0; qt < 2; ++qt)
#pragma unroll
            for (int r = 0; r < 4; ++r) {
                float mx = fmaxf(fmaxf(sc[qt][0][r], sc[qt][1][r]), fmaxf(sc[qt][2][r], sc[qt][3][r]));
#pragma unroll
                for (int mk = 1; mk <= 8; mk <<= 1) mx = fmaxf(mx, __shfl_xor(mx, mk, 64));
                float mn = fmaxf(m_run[qt][r], mx);
                float a = __expf(m_run[qt][r] - mn);
                float ps = 0.f;
#pragma unroll
                for (int nt = 0; nt < 4; ++nt) {
                    float p = __expf(sc[qt][nt][r] - mn);
                    sc[qt][nt][r] = p;
                    ps += p;
                }
#pragma unroll
                for (int mk = 1; mk <= 8; mk <<= 1) ps += __shfl_xor(ps, mk, 64);
                l_run[qt][r] = l_run[qt][r] * a + ps;
                m_run[qt][r] = mn;
                al[qt][r] = a;
            }
        // P -> LDS (bf16), per-wave buffer
#pragma unroll
        for (int qt = 0; qt < 2; ++qt)
#pragma unroll
            for (int nt = 0; nt < 4; ++nt)
#pragma unroll
                for (int r = 0; r < 4; ++r)
                    Pb[w][qt * 16 + quad * 4 + r][nt * 16 + l15] = f2bf(sc[qt][nt][r]);
        __syncthreads();
        // rescale O, then O += P @ V
#pragma unroll
        for (int qt = 0; qt < 2; ++qt) {
#pragma unroll
            for (int dt = 0; dt < 4; ++dt)
#pragma unroll
                for (int r = 0; r < 4; ++r)
                    Oacc[qt][dt][r] *= al[qt][r];
            bf16x8_t pf[2];
#pragma unroll
            for (int ks = 0; ks < 2; ++ks)
                pf[ks] = *(const bf16x8_t*)&Pb[w][qt * 16 + l15][ks * 32 + quad * 8];
#pragma unroll
            for (int dt = 0; dt < 4; ++dt) {
                f32x4_t a = Oacc[qt][dt];
#pragma unroll
                for (int ks = 0; ks < 2; ++ks) {
                    bf16x8_t vf = *(const bf16x8_t*)&Vt[dt * 16 + l15][ks * 32 + quad * 8];
                    a = __builtin_amdgcn_mfma_f32_16x16x32_bf16(pf[ks], vf, a, 0, 0, 0);
                }
                Oacc[qt][dt] = a;
            }
        }
    }
    // write O / l
#pragma unroll
    for (int qt = 0; qt < 2; ++qt)
#pragma unroll
        for (int r = 0; r < 4; ++r) {
            float inv = 1.f / l_run[qt][r];
            int row = n * 128 + w * 32 + qt * 16 + quad * 4 + r;
#pragma unroll
            for (int dt = 0; dt < 4; ++dt)
                out[(size_t)(b * 4096 + row) * 512 + h * 64 + dt * 16 + l15] = f2bf(Oacc[qt][dt][r] * inv);
        }
}

// ---------------- GLU: [16384,1024] -> [16384,512], bf16 ----------------
__global__ __launch_bounds__(256) void k_glu(const bf16* __restrict__ h, bf16* __restrict__ out) {
    int idx = blockIdx.x * 256 + threadIdx.x;
    int m = idx >> 9, c = idx & 511;
    float a = bf2f(h[(size_t)m * 1024 + c]);
    float g = bf2f(h[(size_t)m * 1024 + c + 512]);
    out[idx] = f2bf(a / (1.f + __expf(-g)));
}

// ---------------- depthwise conv (KS=31, pad 15) + BN + SiLU ----------------
__global__ __launch_bounds__(256) void k_conv(const bf16* __restrict__ in, const float* __restrict__ w,
                                              const float* __restrict__ wb, const float* __restrict__ bg,
                                              const float* __restrict__ bb2, const float* __restrict__ bm,
                                              const float* __restrict__ bvv, bf16* __restrict__ out) {
    int idx = blockIdx.x * 256 + threadIdx.x;
    int d = idx & 511, m = idx >> 9, s = m & 4095, bb = m >> 12;
    const bf16* base = in + (size_t)(bb * 4096) * 512 + d;
    float acc = 0.f;
#pragma unroll
    for (int t = 0; t < 31; ++t) {
        int ss = s + t - 15;
        if (ss >= 0 && ss < 4096)
            acc += w[d * 31 + t] * bf2f(base[(size_t)ss * 512]);
    }
    acc += wb[d];
    float sc = bg[d] * rsqrtf(bvv[d] + 1e-5f);
    acc = (acc - bm[d]) * sc + bb2[d];
    acc = acc / (1.f + __expf(-acc));
    out[idx] = f2bf(acc);
}

extern "C" void kernel_launch(void* const* d_in, const int* in_sizes, int n_in,
                              void* d_out, int out_size, void* d_ws, size_t ws_size,
                              hipStream_t stream) {
    (void)in_sizes; (void)n_in; (void)out_size; (void)ws_size;
    const float* x = (const float*)d_in[0];
    char* ws = (char*)d_ws;
    float* xf   = (float*)ws;                      // [0,32M)   fp32 residual
    bf16* ln_bf = (bf16*)(ws + 33554432);          // [32M,48M) LN output (bf16)
    bf16* h_bf  = (bf16*)(ws + 50331648);          // [48M,112M) hidden / q,k,v
    bf16* g_bf  = (bf16*)(ws + 117440512);         // [112M,128M) GLU out
    bf16* t_bf  = (bf16*)(ws + 134217728);         // [128M,144M) attn/conv out
    bf16* wc    = (bf16*)(ws + 150994944);         // [144M,...) transposed bf16 weights
    bf16 *qb = h_bf, *kb = h_bf + 8388608, *vb = h_bf + 16777216;
    bf16* w_f11 = wc;                // [2048][512]
    bf16* w_f12 = wc + 1048576;      // [512][2048]
    bf16* w_f21 = wc + 2097152;      // [2048][512]
    bf16* w_f22 = wc + 3145728;      // [512][2048]
    bf16* w_q   = wc + 4194304;      // [512][512]
    bf16* w_k   = wc + 4456448;
    bf16* w_v   = wc + 4718592;
    bf16* w_o   = wc + 4980736;
    bf16* w_p1  = wc + 5242880;      // [1024][512]
    bf16* w_p2  = wc + 5767168;      // [512][512]

    // weight fp32 -> bf16 transposed [N][K]
    k_f2bt<<<dim3(64, 16), 256, 0, stream>>>((const float*)d_in[3],  w_f11, 512, 2048);
    k_f2bt<<<dim3(16, 64), 256, 0, stream>>>((const float*)d_in[5],  w_f12, 2048, 512);
    k_f2bt<<<dim3(64, 16), 256, 0, stream>>>((const float*)d_in[9],  w_f21, 512, 2048);
    k_f2bt<<<dim3(16, 64), 256, 0, stream>>>((const float*)d_in[11], w_f22, 2048, 512);
    k_f2bt<<<dim3(16, 16), 256, 0, stream>>>((const float*)d_in[15], w_q, 512, 512);
    k_f2bt<<<dim3(16, 16), 256, 0, stream>>>((const float*)d_in[16], w_k, 512, 512);
    k_f2bt<<<dim3(16, 16), 256, 0, stream>>>((const float*)d_in[17], w_v, 512, 512);
    k_f2bt<<<dim3(16, 16), 256, 0, stream>>>((const float*)d_in[18], w_o, 512, 512);
    k_f2bt<<<dim3(32, 16), 256, 0, stream>>>((const float*)d_in[26], w_p1, 512, 1024);
    k_f2bt<<<dim3(16, 16), 256, 0, stream>>>((const float*)d_in[34], w_p2, 512, 512);

    hipMemcpyAsync(xf, x, 33554432, hipMemcpyDeviceToDevice, stream);

    // FFN1: x += 0.5*FFN(LN(x))
    k_ln<true><<<16384, 64, 0, stream>>>(xf, (const float*)d_in[1], (const float*)d_in[2], ln_bf);
    k_gemm<1><<<dim3(16, 128), 256, 0, stream>>>(ln_bf, w_f11, (const float*)d_in[4], h_bf, 16384, 2048, 512, 0.f);
    k_gemm<2><<<dim3(4, 128), 256, 0, stream>>>(h_bf, w_f12, (const float*)d_in[6], xf, 16384, 512, 2048, 0.5f);
    // attention
    k_ln<true><<<16384, 64, 0, stream>>>(xf, (const float*)d_in[13], (const float*)d_in[14], ln_bf);
    k_gemm<0><<<dim3(4, 128), 256, 0, stream>>>(ln_bf, w_q, (const float*)d_in[19], qb, 16384, 512, 512, 0.f);
    k_gemm<0><<<dim3(4, 128), 256, 0, stream>>>(ln_bf, w_k, (const float*)d_in[20], kb, 16384, 512, 512, 0.f);
    k_gemm<0><<<dim3(4, 128), 256, 0, stream>>>(ln_bf, w_v, (const float*)d_in[21], vb, 16384, 512, 512, 0.f);
    k_attn<<<1024, 256, 0, stream>>>(qb, kb, vb, (const float*)d_in[23], t_bf);
    k_gemm<2><<<dim3(4, 128), 256, 0, stream>>>(t_bf, w_o, (const float*)d_in[22], xf, 16384, 512, 512, 1.0f);
    // conv module
    k_ln<true><<<16384, 64, 0, stream>>>(xf, (const float*)d_in[24], (const float*)d_in[25], ln_bf);
    k_gemm<0><<<dim3(8, 128), 256, 0, stream>>>(ln_bf, w_p1, (const float*)d_in[27], h_bf, 16384, 1024, 512, 0.f);
    k_glu<<<32768, 256, 0, stream>>>(h_bf, g_bf);
    k_conv<<<32768, 256, 0, stream>>>(g_bf, (const float*)d_in[28], (const float*)d_in[29], (const float*)d_in[30],
                                      (const float*)d_in[31], (const float*)d_in[32], (const float*)d_in[33], t_bf);
    k_gemm<2><<<dim3(4, 128), 256, 0, stream>>>(t_bf, w_p2, (const float*)d_in[35], xf, 16384, 512, 512, 1.0f);
    // FFN2
    k_ln<true><<<16384, 64, 0, stream>>>(xf, (const float*)d_in[7], (const float*)d_in[8], ln_bf);
    k_gemm<1><<<dim3(16, 128), 256, 0, stream>>>(ln_bf, w_f21, (const float*)d_in[10], h_bf, 16384, 2048, 512, 0.f);
    k_gemm<2><<<dim3(4, 128), 256, 0, stream>>>(h_bf, w_f22, (const float*)d_in[12], xf, 16384, 512, 2048, 0.5f);
    // final LN -> fp32 out
    k_ln<false><<<16384, 64, 0, stream>>>(xf, (const float*)d_in[36], (const float*)d_in[37], d_out);
}

// Round 5
// 775.267 us; speedup vs baseline: 2.7063x; 1.4130x over previous
//
#include <hip/hip_runtime.h>
#include <hip/hip_bf16.h>
#include <math.h>

// ConformerBlock on MI355X. B=4, S=4096, D=512, H=8, Hd=64, CTX=128, FFN=2048, KS=31.
// fp32 inputs/outputs. bf16 MFMA GEMMs (m97-style 128x128 tile + global_load_lds),
// MFMA flash attention, tiled sliding-window depthwise conv. Residual fp32 in ws.

using bf16 = __hip_bfloat16;
typedef __bf16 bf16x8_t __attribute__((ext_vector_type(8)));
typedef float f32x4_t __attribute__((ext_vector_type(4)));

static __device__ __forceinline__ float bf2f(bf16 v) { return __bfloat162float(v); }
static __device__ __forceinline__ bf16 f2bf(float v) { return __float2bfloat16(v); }

#define GLOAD_LDS16(g, l)                                                            \
    __builtin_amdgcn_global_load_lds((const __attribute__((address_space(1))) void*)(g), \
                                     (__attribute__((address_space(3))) void*)(l), 16, 0, 0)

// ---------------- fp32 [K][N] -> bf16 transposed [N][K] ----------------
__global__ __launch_bounds__(256) void k_f2bt(const float* __restrict__ in, bf16* __restrict__ out,
                                              int K, int N) {
    __shared__ float t[32][33];
    int c = threadIdx.x & 31, r0 = threadIdx.x >> 5;
    int kb = blockIdx.y * 32, nb = blockIdx.x * 32;
#pragma unroll
    for (int i = 0; i < 4; ++i)
        t[r0 + i * 8][c] = in[(size_t)(kb + r0 + i * 8) * N + nb + c];
    __syncthreads();
#pragma unroll
    for (int i = 0; i < 4; ++i)
        out[(size_t)(nb + r0 + i * 8) * K + kb + c] = f2bf(t[c][r0 + i * 8]);
}

// ---------------- LayerNorm: fp32 in -> bf16 (or fp32) out, one wave per row ----------------
template <bool BF16OUT>
__global__ __launch_bounds__(64) void k_ln(const float* __restrict__ x, const float* __restrict__ g,
                                           const float* __restrict__ b, void* __restrict__ outp) {
    int row = blockIdx.x, t = threadIdx.x;
    const float* xr = x + (size_t)row * 512 + t * 8;
    float4 v0 = *(const float4*)xr;
    float4 v1 = *(const float4*)(xr + 4);
    float vals[8] = {v0.x, v0.y, v0.z, v0.w, v1.x, v1.y, v1.z, v1.w};
    float s = 0.f, ss = 0.f;
#pragma unroll
    for (int j = 0; j < 8; ++j) { s += vals[j]; ss += vals[j] * vals[j]; }
#pragma unroll
    for (int o = 32; o > 0; o >>= 1) { s += __shfl_xor(s, o, 64); ss += __shfl_xor(ss, o, 64); }
    float mean = s * (1.0f / 512.0f);
    float var  = ss * (1.0f / 512.0f) - mean * mean;
    float r = rsqrtf(var + 1e-5f);
    float4 g0 = *(const float4*)(g + t * 8);
    float4 g1 = *(const float4*)(g + t * 8 + 4);
    float4 b0 = *(const float4*)(b + t * 8);
    float4 b1 = *(const float4*)(b + t * 8 + 4);
    float gv[8] = {g0.x, g0.y, g0.z, g0.w, g1.x, g1.y, g1.z, g1.w};
    float bv[8] = {b0.x, b0.y, b0.z, b0.w, b1.x, b1.y, b1.z, b1.w};
    float ov[8];
#pragma unroll
    for (int j = 0; j < 8; ++j) ov[j] = (vals[j] - mean) * r * gv[j] + bv[j];
    if (BF16OUT) {
        union { uint4 u; bf16 h[8]; } oo;
#pragma unroll
        for (int j = 0; j < 8; ++j) oo.h[j] = f2bf(ov[j]);
        *(uint4*)((bf16*)outp + (size_t)row * 512 + t * 8) = oo.u;
    } else {
        float* op = (float*)outp + (size_t)row * 512 + t * 8;
        *(float4*)op = make_float4(ov[0], ov[1], ov[2], ov[3]);
        *(float4*)(op + 4) = make_float4(ov[4], ov[5], ov[6], ov[7]);
    }
}

// ---------------- m97-style GEMM: C = A[M,K] @ Bt[N,K]^T + bias, 128x128 tile ----------------
// MODE 0: bf16 store. MODE 1: exact GELU -> bf16. MODE 2: fp32 out += scale*(acc+bias).
template <int MODE>
__global__ __launch_bounds__(256) void k_gemm(const bf16* __restrict__ A, const bf16* __restrict__ Bt,
                                              const float* __restrict__ bias, void* __restrict__ outp,
                                              int M, int N, int K, float scale) {
    __shared__ __align__(16) bf16 As[128 * 32];
    __shared__ __align__(16) bf16 Bs[128 * 32];
    int bn = blockIdx.x * 128, bm = blockIdx.y * 128;
    int tid = threadIdx.x, w = tid >> 6, l = tid & 63;
    int l15 = l & 15, quad = l >> 4;
    int wm = (w >> 1) * 64, wn = (w & 1) * 64;
    f32x4_t acc[4][4] = {};
    const bf16* ag = A + (size_t)(bm + w * 32 + (l >> 2)) * K + (l & 3) * 8;
    const bf16* bg = Bt + (size_t)(bn + w * 32 + (l >> 2)) * K + (l & 3) * 8;
    bf16* asl = As + w * 32 * 32;   // wave-uniform LDS base
    bf16* bsl = Bs + w * 32 * 32;

    for (int k0 = 0; k0 < K; k0 += 32) {
        __syncthreads();
#pragma unroll
        for (int j = 0; j < 2; ++j) {
            GLOAD_LDS16(ag + (size_t)j * 16 * K + k0, asl + j * 16 * 32);
            GLOAD_LDS16(bg + (size_t)j * 16 * K + k0, bsl + j * 16 * 32);
        }
        __syncthreads();
        bf16x8_t af[4], bfr[4];
#pragma unroll
        for (int tm = 0; tm < 4; ++tm)
            af[tm] = *(const bf16x8_t*)(As + (wm + tm * 16 + l15) * 32 + quad * 8);
#pragma unroll
        for (int tn = 0; tn < 4; ++tn)
            bfr[tn] = *(const bf16x8_t*)(Bs + (wn + tn * 16 + l15) * 32 + quad * 8);
#pragma unroll
        for (int tm = 0; tm < 4; ++tm)
#pragma unroll
            for (int tn = 0; tn < 4; ++tn)
                acc[tm][tn] = __builtin_amdgcn_mfma_f32_16x16x32_bf16(af[tm], bfr[tn], acc[tm][tn], 0, 0, 0);
    }
#pragma unroll
    for (int tm = 0; tm < 4; ++tm)
#pragma unroll
        for (int tn = 0; tn < 4; ++tn) {
            int gcol = bn + wn + tn * 16 + l15;
            float bv = bias[gcol];
#pragma unroll
            for (int r = 0; r < 4; ++r) {
                int grow = bm + wm + tm * 16 + quad * 4 + r;
                float vv = acc[tm][tn][r] + bv;
                if (MODE == 0) {
                    ((bf16*)outp)[(size_t)grow * N + gcol] = f2bf(vv);
                } else if (MODE == 1) {
                    float gl = 0.5f * vv * (1.0f + erff(vv * 0.70710678118654752f));
                    ((bf16*)outp)[(size_t)grow * N + gcol] = f2bf(gl);
                } else {
                    ((float*)outp)[(size_t)grow * N + gcol] += scale * vv;
                }
            }
        }
}

// ---------------- MFMA flash attention over 384-key windows ----------------
__global__ __launch_bounds__(256) void k_attn(const bf16* __restrict__ q, const bf16* __restrict__ k,
                                              const bf16* __restrict__ v, const float* __restrict__ rel_bias,
                                              bf16* __restrict__ out) {
    __shared__ __align__(16) bf16 Qs[128][72];
    __shared__ __align__(16) bf16 Ks[64][72];
    __shared__ __align__(16) bf16 Vt[64][72];
    __shared__ __align__(16) bf16 Pb[4][32][72];
    __shared__ float relb[257];
    int blk = blockIdx.x;
    int n = blk & 31, h = (blk >> 5) & 7, b = blk >> 8;
    int tid = threadIdx.x, w = tid >> 6, lane = tid & 63;
    int l15 = lane & 15, quad = lane >> 4;
    for (int i = tid; i < 257; i += 256) relb[i] = rel_bias[h * 257 + i];
    {   // stage Q block: 128 rows x 64 cols = 1024 uint4 stores
        const bf16* qg = q + (size_t)(b * 4096 + n * 128) * 512 + h * 64;
#pragma unroll
        for (int i = 0; i < 4; ++i) {
            int slot = tid + 256 * i;
            int row = slot >> 3, col = (slot & 7) * 8;
            *(uint4*)&Qs[row][col] = *(const uint4*)(qg + (size_t)row * 512 + col);
        }
    }
    float m_run[2][4], l_run[2][4];
#pragma unroll
    for (int qt = 0; qt < 2; ++qt)
#pragma unroll
        for (int r = 0; r < 4; ++r) { m_run[qt][r] = -1e30f; l_run[qt][r] = 0.f; }
    f32x4_t Oacc[2][4] = {};
    int kv0 = n * 128 - 128;
    for (int ch = 0; ch < 6; ++ch) {
        int kst = kv0 + ch * 64;
        if (kst < 0 || kst >= 4096) continue;
        __syncthreads();
        {   // stage K chunk [64 keys][64 d]
#pragma unroll
            for (int i = 0; i < 2; ++i) {
                int slot = tid + 256 * i;
                int row = slot >> 3, col = (slot & 7) * 8;
                *(uint4*)&Ks[row][col] = *(const uint4*)(k + (size_t)(b * 4096 + kst + row) * 512 + h * 64 + col);
            }
        }
        {   // stage V chunk transposed: Vt[d][key]
            int key = tid >> 2, c0 = (tid & 3) * 16;
            union { uint4 u[2]; bf16 hh[16]; } tv;
            const bf16* vg = v + (size_t)(b * 4096 + kst + key) * 512 + h * 64 + c0;
            tv.u[0] = *(const uint4*)vg;
            tv.u[1] = *(const uint4*)(vg + 8);
#pragma unroll
            for (int j = 0; j < 16; ++j) Vt[c0 + j][key] = tv.hh[j];
        }
        __syncthreads();
        bf16x8_t qf[2][2];
#pragma unroll
        for (int qt = 0; qt < 2; ++qt)
#pragma unroll
            for (int ks = 0; ks < 2; ++ks)
                qf[qt][ks] = *(const bf16x8_t*)&Qs[w * 32 + qt * 16 + l15][ks * 32 + quad * 8];
        float sc[2][4][4];
#pragma unroll
        for (int qt = 0; qt < 2; ++qt)
#pragma unroll
            for (int nt = 0; nt < 4; ++nt) {
                f32x4_t a = {};
#pragma unroll
                for (int ks = 0; ks < 2; ++ks) {
                    bf16x8_t kf = *(const bf16x8_t*)&Ks[nt * 16 + l15][ks * 32 + quad * 8];
                    a = __builtin_amdgcn_mfma_f32_16x16x32_bf16(qf[qt][ks], kf, a, 0, 0, 0);
                }
#pragma unroll
                for (int r = 0; r < 4; ++r) sc[qt][nt][r] = a[r];
            }
#pragma unroll
        for (int qt = 0; qt < 2; ++qt)
#pragma unroll
            for (int nt = 0; nt < 4; ++nt)
#pragma unroll
                for (int r = 0; r < 4; ++r) {
                    int qrow = w * 32 + qt * 16 + quad * 4 + r;
                    int rel = ch * 64 + nt * 16 + l15 - 128 - qrow;
                    int idx = rel + 128; idx = idx < 0 ? 0 : (idx > 256 ? 256 : idx);
                    float s = sc[qt][nt][r] * 0.125f + relb[idx];
                    sc[qt][nt][r] = (rel >= -128 && rel <= 128) ? s : -INFINITY;
                }
        float al[2][4];
#pragma unroll
        for (int qt = 0; qt < 2; ++qt)
#pragma unroll
            for (int r = 0; r < 4; ++r) {
                float mx = fmaxf(fmaxf(sc[qt][0][r], sc[qt][1][r]), fmaxf(sc[qt][2][r], sc[qt][3][r]));
#pragma unroll
                for (int mk = 1; mk <= 8; mk <<= 1) mx = fmaxf(mx, __shfl_xor(mx, mk, 64));
                float mn = fmaxf(m_run[qt][r], mx);
                float a = __expf(m_run[qt][r] - mn);
                float ps = 0.f;
#pragma unroll
                for (int nt = 0; nt < 4; ++nt) {
                    float p = __expf(sc[qt][nt][r] - mn);
                    sc[qt][nt][r] = p;
                    ps += p;
                }
#pragma unroll
                for (int mk = 1; mk <= 8; mk <<= 1) ps += __shfl_xor(ps, mk, 64);
                l_run[qt][r] = l_run[qt][r] * a + ps;
                m_run[qt][r] = mn;
                al[qt][r] = a;
            }
#pragma unroll
        for (int qt = 0; qt < 2; ++qt)
#pragma unroll
            for (int nt = 0; nt < 4; ++nt)
#pragma unroll
                for (int r = 0; r < 4; ++r)
                    Pb[w][qt * 16 + quad * 4 + r][nt * 16 + l15] = f2bf(sc[qt][nt][r]);
        __syncthreads();
#pragma unroll
        for (int qt = 0; qt < 2; ++qt) {
#pragma unroll
            for (int dt = 0; dt < 4; ++dt)
#pragma unroll
                for (int r = 0; r < 4; ++r)
                    Oacc[qt][dt][r] *= al[qt][r];
            bf16x8_t pf[2];
#pragma unroll
            for (int ks = 0; ks < 2; ++ks)
                pf[ks] = *(const bf16x8_t*)&Pb[w][qt * 16 + l15][ks * 32 + quad * 8];
#pragma unroll
            for (int dt = 0; dt < 4; ++dt) {
                f32x4_t a = Oacc[qt][dt];
#pragma unroll
                for (int ks = 0; ks < 2; ++ks) {
                    bf16x8_t vf = *(const bf16x8_t*)&Vt[dt * 16 + l15][ks * 32 + quad * 8];
                    a = __builtin_amdgcn_mfma_f32_16x16x32_bf16(pf[ks], vf, a, 0, 0, 0);
                }
                Oacc[qt][dt] = a;
            }
        }
    }
#pragma unroll
    for (int qt = 0; qt < 2; ++qt)
#pragma unroll
        for (int r = 0; r < 4; ++r) {
            float inv = 1.f / l_run[qt][r];
            int row = n * 128 + w * 32 + qt * 16 + quad * 4 + r;
#pragma unroll
            for (int dt = 0; dt < 4; ++dt)
                out[(size_t)(b * 4096 + row) * 512 + h * 64 + dt * 16 + l15] = f2bf(Oacc[qt][dt][r] * inv);
        }
}

// ---------------- GLU: [16384,1024] -> [16384,512], bf16 ----------------
__global__ __launch_bounds__(256) void k_glu(const bf16* __restrict__ h, bf16* __restrict__ out) {
    int idx = blockIdx.x * 256 + threadIdx.x;
    int m = idx >> 9, c = idx & 511;
    float a = bf2f(h[(size_t)m * 1024 + c]);
    float g = bf2f(h[(size_t)m * 1024 + c + 512]);
    out[idx] = f2bf(a / (1.f + __expf(-g)));
}

// ---------------- tiled depthwise conv (KS=31) + BN + SiLU ----------------
// grid: (D/64, S/64, B). Block 256: 4 s-chunks of 16 x 64 channels.
// Weights staged in LDS once (coalesced), hoisted to registers; input is a
// 46-value register sliding window of coalesced 128B/wave loads.
__global__ __launch_bounds__(256) void k_conv(const bf16* __restrict__ in, const float* __restrict__ w,
                                              const float* __restrict__ wb, const float* __restrict__ bg,
                                              const float* __restrict__ bb2, const float* __restrict__ bm,
                                              const float* __restrict__ bvv, bf16* __restrict__ out) {
    __shared__ float wl[64 * 31];
    int d0 = blockIdx.x * 64, s0 = blockIdx.y * 64, b = blockIdx.z;
    for (int i = threadIdx.x; i < 64 * 31; i += 256) wl[i] = w[d0 * 31 + i];
    __syncthreads();
    int dl = threadIdx.x & 63, chunk = threadIdx.x >> 6;
    int d = d0 + dl;
    int s00 = s0 + chunk * 16;
    float wr[31];
#pragma unroll
    for (int t = 0; t < 31; ++t) wr[t] = wl[dl * 31 + t];
    float xw[46];
    const bf16* base = in + (size_t)(b * 4096) * 512 + d;
#pragma unroll
    for (int i = 0; i < 46; ++i) {
        int s = s00 - 15 + i;
        xw[i] = (s >= 0 && s < 4096) ? bf2f(base[(size_t)s * 512]) : 0.f;
    }
    float scv = bg[d] * rsqrtf(bvv[d] + 1e-5f);
    float wbd = wb[d], bmd = bm[d], bbd = bb2[d];
    bf16* op = out + (size_t)(b * 4096 + s00) * 512 + d;
#pragma unroll
    for (int j = 0; j < 16; ++j) {
        float acc = 0.f;
#pragma unroll
        for (int t = 0; t < 31; ++t) acc += wr[t] * xw[j + t];
        acc += wbd;
        acc = (acc - bmd) * scv + bbd;
        acc = acc / (1.f + __expf(-acc));
        op[(size_t)j * 512] = f2bf(acc);
    }
}

extern "C" void kernel_launch(void* const* d_in, const int* in_sizes, int n_in,
                              void* d_out, int out_size, void* d_ws, size_t ws_size,
                              hipStream_t stream) {
    (void)in_sizes; (void)n_in; (void)out_size; (void)ws_size;
    const float* x = (const float*)d_in[0];
    char* ws = (char*)d_ws;
    float* xf   = (float*)ws;                      // [0,32M)   fp32 residual
    bf16* ln_bf = (bf16*)(ws + 33554432);          // [32M,48M) LN output (bf16)
    bf16* h_bf  = (bf16*)(ws + 50331648);          // [48M,112M) hidden / q,k,v
    bf16* g_bf  = (bf16*)(ws + 117440512);         // [112M,128M) GLU out
    bf16* t_bf  = (bf16*)(ws + 134217728);         // [128M,144M) attn/conv out
    bf16* wc    = (bf16*)(ws + 150994944);         // [144M,...) transposed bf16 weights
    bf16 *qb = h_bf, *kb = h_bf + 8388608, *vb = h_bf + 16777216;
    bf16* w_f11 = wc;                // [2048][512]
    bf16* w_f12 = wc + 1048576;      // [512][2048]
    bf16* w_f21 = wc + 2097152;      // [2048][512]
    bf16* w_f22 = wc + 3145728;      // [512][2048]
    bf16* w_q   = wc + 4194304;      // [512][512]
    bf16* w_k   = wc + 4456448;
    bf16* w_v   = wc + 4718592;
    bf16* w_o   = wc + 4980736;
    bf16* w_p1  = wc + 5242880;      // [1024][512]
    bf16* w_p2  = wc + 5767168;      // [512][512]

    // weight fp32 -> bf16 transposed [N][K]
    k_f2bt<<<dim3(64, 16), 256, 0, stream>>>((const float*)d_in[3],  w_f11, 512, 2048);
    k_f2bt<<<dim3(16, 64), 256, 0, stream>>>((const float*)d_in[5],  w_f12, 2048, 512);
    k_f2bt<<<dim3(64, 16), 256, 0, stream>>>((const float*)d_in[9],  w_f21, 512, 2048);
    k_f2bt<<<dim3(16, 64), 256, 0, stream>>>((const float*)d_in[11], w_f22, 2048, 512);
    k_f2bt<<<dim3(16, 16), 256, 0, stream>>>((const float*)d_in[15], w_q, 512, 512);
    k_f2bt<<<dim3(16, 16), 256, 0, stream>>>((const float*)d_in[16], w_k, 512, 512);
    k_f2bt<<<dim3(16, 16), 256, 0, stream>>>((const float*)d_in[17], w_v, 512, 512);
    k_f2bt<<<dim3(16, 16), 256, 0, stream>>>((const float*)d_in[18], w_o, 512, 512);
    k_f2bt<<<dim3(32, 16), 256, 0, stream>>>((const float*)d_in[26], w_p1, 512, 1024);
    k_f2bt<<<dim3(16, 16), 256, 0, stream>>>((const float*)d_in[34], w_p2, 512, 512);

    hipMemcpyAsync(xf, x, 33554432, hipMemcpyDeviceToDevice, stream);

    // FFN1: x += 0.5*FFN(LN(x))
    k_ln<true><<<16384, 64, 0, stream>>>(xf, (const float*)d_in[1], (const float*)d_in[2], ln_bf);
    k_gemm<1><<<dim3(16, 128), 256, 0, stream>>>(ln_bf, w_f11, (const float*)d_in[4], h_bf, 16384, 2048, 512, 0.f);
    k_gemm<2><<<dim3(4, 128), 256, 0, stream>>>(h_bf, w_f12, (const float*)d_in[6], xf, 16384, 512, 2048, 0.5f);
    // attention
    k_ln<true><<<16384, 64, 0, stream>>>(xf, (const float*)d_in[13], (const float*)d_in[14], ln_bf);
    k_gemm<0><<<dim3(4, 128), 256, 0, stream>>>(ln_bf, w_q, (const float*)d_in[19], qb, 16384, 512, 512, 0.f);
    k_gemm<0><<<dim3(4, 128), 256, 0, stream>>>(ln_bf, w_k, (const float*)d_in[20], kb, 16384, 512, 512, 0.f);
    k_gemm<0><<<dim3(4, 128), 256, 0, stream>>>(ln_bf, w_v, (const float*)d_in[21], vb, 16384, 512, 512, 0.f);
    k_attn<<<1024, 256, 0, stream>>>(qb, kb, vb, (const float*)d_in[23], t_bf);
    k_gemm<2><<<dim3(4, 128), 256, 0, stream>>>(t_bf, w_o, (const float*)d_in[22], xf, 16384, 512, 512, 1.0f);
    // conv module
    k_ln<true><<<16384, 64, 0, stream>>>(xf, (const float*)d_in[24], (const float*)d_in[25], ln_bf);
    k_gemm<0><<<dim3(8, 128), 256, 0, stream>>>(ln_bf, w_p1, (const float*)d_in[27], h_bf, 16384, 1024, 512, 0.f);
    k_glu<<<32768, 256, 0, stream>>>(h_bf, g_bf);
    k_conv<<<dim3(8, 64, 4), 256, 0, stream>>>(g_bf, (const float*)d_in[28], (const float*)d_in[29], (const float*)d_in[30],
                                               (const float*)d_in[31], (const float*)d_in[32], (const float*)d_in[33], t_bf);
    k_gemm<2><<<dim3(4, 128), 256, 0, stream>>>(t_bf, w_p2, (const float*)d_in[35], xf, 16384, 512, 512, 1.0f);
    // FFN2
    k_ln<true><<<16384, 64, 0, stream>>>(xf, (const float*)d_in[7], (const float*)d_in[8], ln_bf);
    k_gemm<1><<<dim3(16, 128), 256, 0, stream>>>(ln_bf, w_f21, (const float*)d_in[10], h_bf, 16384, 2048, 512, 0.f);
    k_gemm<2><<<dim3(4, 128), 256, 0, stream>>>(h_bf, w_f22, (const float*)d_in[12], xf, 16384, 512, 2048, 0.5f);
    // final LN -> fp32 out
    k_ln<false><<<16384, 64, 0, stream>>>(xf, (const float*)d_in[36], (const float*)d_in[37], d_out);
}